// Round 1
// baseline (614.804 us; speedup 1.0000x reference)
//
#include <hip/hip_runtime.h>
#include <math.h>

#define NN 4096      // nodes
#define CC 512       // concat dim = 8 heads * 64
#define MB (1024*1024)

static __device__ __forceinline__ float lrelu(float x){ return x > 0.f ? x : 0.2f*x; }
static __device__ __forceinline__ float elu1(float x){ return x > 0.f ? x : (__expf(x)-1.f); }

// ---- repack W_att [8][512][64] -> W_all [512][512]  (W_all[k][hd*64+f])
__global__ void k_repack(const float* __restrict__ Watt, float* __restrict__ Wall){
    int idx = blockIdx.x*256 + threadIdx.x;            // < 512*512
    int k = idx >> 9, c = idx & 511;
    Wall[idx] = Watt[(c>>6)*(512*64) + k*64 + (c&63)];
}

// ---- generic f32 GEMM: C[M,N]=A[M,K]@B[K,N], row-major. BM=64, BK=16, TM=4.
template<int BN, int TN>
__global__ __launch_bounds__(256) void k_gemm(const float* __restrict__ A,
                                              const float* __restrict__ B,
                                              float* __restrict__ C,
                                              int M, int N, int K){
    constexpr int BM = 64, BK = 16, TM = 4;
    __shared__ float As[BK][BM + 4];
    __shared__ float Bs[BK][BN];
    const int t = threadIdx.x;
    const int i0 = blockIdx.x*BM, j0 = blockIdx.y*BN;
    constexpr int nx = BN / TN;
    const int ty = t / nx, tx = t % nx;
    float acc[TM][TN];
    #pragma unroll
    for(int a=0;a<TM;a++){
        #pragma unroll
        for(int b=0;b<TN;b++) acc[a][b] = 0.f;
    }
    const int ai = t >> 2, ak = (t & 3)*4;
    for(int k0 = 0; k0 < K; k0 += BK){
        __syncthreads();
        float4 av = *(const float4*)&A[(size_t)(i0+ai)*K + k0 + ak];
        As[ak+0][ai]=av.x; As[ak+1][ai]=av.y; As[ak+2][ai]=av.z; As[ak+3][ai]=av.w;
        if constexpr (BN == 64){
            int bk = t >> 4, bj = (t & 15)*4;
            *(float4*)&Bs[bk][bj] = *(const float4*)&B[(size_t)(k0+bk)*N + j0 + bj];
        } else {            // BN == 32
            if (t < 128){
                int bk = t >> 3, bj = (t & 7)*4;
                *(float4*)&Bs[bk][bj] = *(const float4*)&B[(size_t)(k0+bk)*N + j0 + bj];
            }
        }
        __syncthreads();
        #pragma unroll
        for(int k=0;k<BK;k++){
            float4 a4 = *(const float4*)&As[k][ty*TM];
            float ar[4] = {a4.x, a4.y, a4.z, a4.w};
            if constexpr (TN == 4){
                float4 b4 = *(const float4*)&Bs[k][tx*4];
                float br[4] = {b4.x, b4.y, b4.z, b4.w};
                #pragma unroll
                for(int a=0;a<TM;a++){
                    #pragma unroll
                    for(int b=0;b<4;b++) acc[a][b] += ar[a]*br[b];
                }
            } else {
                float2 b2 = *(const float2*)&Bs[k][tx*2];
                #pragma unroll
                for(int a=0;a<TM;a++){ acc[a][0] += ar[a]*b2.x; acc[a][1] += ar[a]*b2.y; }
            }
        }
    }
    #pragma unroll
    for(int a=0;a<TM;a++){
        float* cp = &C[(size_t)(i0 + ty*TM + a)*N + j0 + tx*TN];
        if constexpr (TN == 4){
            float4 v = {acc[a][0], acc[a][1], acc[a][2], acc[a][3]};
            *(float4*)cp = v;
        } else {
            float2 v = {acc[a][0], acc[a][1]};
            *(float2*)cp = v;
        }
    }
}

// ---- scores layer1: s_src[hd][i], s_dst[hd][i]
__global__ void k_scores1(const float* __restrict__ hall, const float* __restrict__ aatt,
                          float* __restrict__ ssrc, float* __restrict__ sdst){
    int t = threadIdx.x;
    int hd = t & 7, il = t >> 3;
    int i = blockIdx.x*32 + il;
    const float4* h4 = (const float4*)&hall[(size_t)i*CC + hd*64];
    const float4* a1 = (const float4*)&aatt[hd*128];
    const float4* a2 = (const float4*)&aatt[hd*128 + 64];
    float ss = 0.f, sd = 0.f;
    #pragma unroll
    for(int q=0;q<16;q++){
        float4 h = h4[q], u = a1[q], v = a2[q];
        ss += h.x*u.x + h.y*u.y + h.z*u.z + h.w*u.w;
        sd += h.x*v.x + h.y*v.y + h.z*v.z + h.w*v.w;
    }
    ssrc[hd*NN + i] = ss;
    sdst[hd*NN + i] = sd;
}

#define FMA4(A, W) { (A).x += (W)*hv.x; (A).y += (W)*hv.y; (A).z += (W)*hv.z; (A).w += (W)*hv.w; }

// ---- attention layer1: pnum[jc][i][c] / pden[jc][hd][i] partials.
// i-tile=32, j-tile=16, jchunk=1024 (blockIdx.y in 0..3). block=256.
__global__ __launch_bounds__(256) void k_attn1(const float* __restrict__ hall,
        const float* __restrict__ ssrc, const float* __restrict__ sdst,
        const int* __restrict__ adj,
        float* __restrict__ pnum, float* __restrict__ pden){
    const int t = threadIdx.x;
    const int i0 = blockIdx.x*32;
    const int jc = blockIdx.y;
    // FMA-phase ids: thread owns (head hd, i-half, 4 feats)
    const int hd = t >> 5, r = t & 31, ihalf = r >> 4, fq = r & 15;
    // w-phase ids: thread owns (head whd, row wii) -> also accumulates denom
    const int whd = t >> 5, wii = t & 31;
    __shared__ float hs[16*512];        // h tile [jj][c]   32KB
    __shared__ float ws[8*16*32];       // w tile [hd][jj][ii] 16KB
    float4 acc[16];
    #pragma unroll
    for(int a=0;a<16;a++) acc[a] = make_float4(0.f,0.f,0.f,0.f);
    float den = 0.f;
    const float ssrc_t = ssrc[whd*NN + i0 + wii];
    float4* hs4 = (float4*)hs;
    const float4* hg4 = (const float4*)hall;

    for(int jt=0; jt<64; ++jt){
        const int j0 = jc*1024 + jt*16;
        __syncthreads();                               // prev-tile reads done
        // stage h tile (16 rows x 512 cols), coalesced float4
        #pragma unroll
        for(int r8=0;r8<8;r8++)
            hs4[r8*256 + t] = hg4[(size_t)j0*128 + r8*256 + t];
        // w phase: compute w[whd][jj][wii] for jj=0..15, accumulate denom
        {
            const size_t arow = (size_t)(i0 + wii)*NN + j0;
            const int4 a0 = *(const int4*)&adj[arow + 0];
            const int4 a1 = *(const int4*)&adj[arow + 4];
            const int4 a2 = *(const int4*)&adj[arow + 8];
            const int4 a3 = *(const int4*)&adj[arow + 12];
            int am[16] = {a0.x,a0.y,a0.z,a0.w, a1.x,a1.y,a1.z,a1.w,
                          a2.x,a2.y,a2.z,a2.w, a3.x,a3.y,a3.z,a3.w};
            #pragma unroll
            for(int jj=0;jj<16;jj++){
                float e = lrelu(ssrc_t + sdst[whd*NN + j0 + jj]);
                float w = (am[jj] > 0) ? __expf(e) : 0.f;
                ws[(whd*16 + jj)*32 + wii] = w;
                den += w;
            }
        }
        __syncthreads();
        // FMA phase: acc[ii] += w[hd][jj][ihalf*16+ii] * h[jj][hd*64+fq*4..+3]
        for(int jj=0;jj<16;jj++){
            float4 hv = hs4[jj*128 + hd*16 + fq];
            const float4* wrow = (const float4*)&ws[(hd*16 + jj)*32 + ihalf*16];
            #pragma unroll
            for(int q=0;q<4;q++){
                float4 w4 = wrow[q];
                FMA4(acc[q*4+0], w4.x);
                FMA4(acc[q*4+1], w4.y);
                FMA4(acc[q*4+2], w4.z);
                FMA4(acc[q*4+3], w4.w);
            }
        }
    }
    // write partials
    float4* pn4 = (float4*)pnum;
    #pragma unroll
    for(int ii=0;ii<16;ii++){
        size_t row = (size_t)jc*NN + i0 + ihalf*16 + ii;
        pn4[row*128 + hd*16 + fq] = acc[ii];
    }
    pden[((size_t)jc*8 + whd)*NN + i0 + wii] = den;
}

// ---- reduce layer1: hcat[i][c] = elu( sum(pnum)/sum(pden) )
__global__ void k_reduce1(const float* __restrict__ pnum, const float* __restrict__ pden,
                          float* __restrict__ hcat){
    int idx = blockIdx.x*256 + threadIdx.x;           // < 4096*512
    int i = idx >> 9, c = idx & 511, hd = c >> 6;
    float s = 0.f, d = 0.f;
    #pragma unroll
    for(int jc=0;jc<4;jc++){
        s += pnum[((size_t)jc*NN + i)*512 + c];
        d += pden[((size_t)jc*8 + hd)*NN + i];
    }
    hcat[idx] = elu1(s/d);
}

// ---- scores layer2
__global__ void k_scores2(const float* __restrict__ h2, const float* __restrict__ aout,
                          float* __restrict__ ss2, float* __restrict__ sd2){
    int i = blockIdx.x*256 + threadIdx.x;
    const float4* h4 = (const float4*)&h2[(size_t)i*32];
    const float4* a1 = (const float4*)aout;
    const float4* a2 = (const float4*)&aout[32];
    float ss = 0.f, sd = 0.f;
    #pragma unroll
    for(int q=0;q<8;q++){
        float4 h = h4[q], u = a1[q], v = a2[q];
        ss += h.x*u.x + h.y*u.y + h.z*u.z + h.w*u.w;
        sd += h.x*v.x + h.y*v.y + h.z*v.z + h.w*v.w;
    }
    ss2[i] = ss; sd2[i] = sd;
}

// ---- attention layer2: i-tile=64, j-tile=16, jchunk=512 (blockIdx.y 0..7)
__global__ __launch_bounds__(256) void k_attn2(const float* __restrict__ h2,
        const float* __restrict__ ss2, const float* __restrict__ sd2,
        const int* __restrict__ adj,
        float* __restrict__ pnum2, float* __restrict__ pden2){
    const int t = threadIdx.x;
    const int i0 = blockIdx.x*64;
    const int jc = blockIdx.y;
    const int fq = t & 7, isub = t >> 3;        // FMA ids: i = i0+isub*2+{0,1}
    const int wii = t & 63, wjq = t >> 6;       // w ids
    __shared__ float h2s[16*32];
    __shared__ float ws2[16*64];                // [jj][ii]
    __shared__ float dpart[4][64];
    float4 acc0 = make_float4(0.f,0.f,0.f,0.f);
    float4 acc1 = make_float4(0.f,0.f,0.f,0.f);
    float den = 0.f;
    const float ssrc_t = ss2[i0 + wii];
    float4* h2s4 = (float4*)h2s;
    const float4* hg4 = (const float4*)h2;

    for(int jt=0; jt<32; ++jt){
        const int j0 = jc*512 + jt*16;
        __syncthreads();
        if (t < 128) h2s4[t] = hg4[(size_t)j0*8 + t];
        {
            const int4 a4 = *(const int4*)&adj[(size_t)(i0+wii)*NN + j0 + wjq*4];
            int am[4] = {a4.x, a4.y, a4.z, a4.w};
            #pragma unroll
            for(int m=0;m<4;m++){
                int jj = wjq*4 + m;
                float e = lrelu(ssrc_t + sd2[j0 + jj]);
                float w = (am[m] > 0) ? __expf(e) : 0.f;
                ws2[jj*64 + wii] = w;
                den += w;
            }
        }
        __syncthreads();
        #pragma unroll
        for(int jj=0;jj<16;jj++){
            float4 hv = h2s4[jj*8 + fq];
            float2 w2 = *(const float2*)&ws2[jj*64 + isub*2];
            FMA4(acc0, w2.x);
            FMA4(acc1, w2.y);
        }
    }
    float4* pn4 = (float4*)pnum2;
    size_t r0 = (size_t)jc*NN + i0 + isub*2;
    pn4[r0*8 + fq] = acc0;
    pn4[(r0+1)*8 + fq] = acc1;
    dpart[wjq][wii] = den;
    __syncthreads();
    if (t < 64)
        pden2[(size_t)jc*NN + i0 + t] = dpart[0][t] + dpart[1][t] + dpart[2][t] + dpart[3][t];
}

// ---- reduce layer2 -> final output
__global__ void k_reduce2(const float* __restrict__ pnum2, const float* __restrict__ pden2,
                          float* __restrict__ out){
    int idx = blockIdx.x*256 + threadIdx.x;       // < 4096*32
    int i = idx >> 5;
    float s = 0.f, d = 0.f;
    #pragma unroll
    for(int jc=0;jc<8;jc++){
        s += pnum2[(size_t)jc*NN*32 + idx];
        d += pden2[(size_t)jc*NN + i];
    }
    out[idx] = elu1(s/d);
}

extern "C" void kernel_launch(void* const* d_in, const int* in_sizes, int n_in,
                              void* d_out, int out_size, void* d_ws, size_t ws_size,
                              hipStream_t stream){
    const float* x    = (const float*)d_in[0];
    const int*   adj  = (const int*)  d_in[1];
    const float* Watt = (const float*)d_in[2];
    const float* aatt = (const float*)d_in[3];
    const float* Wout = (const float*)d_in[4];
    const float* aout = (const float*)d_in[5];
    float* out = (float*)d_out;
    char* ws = (char*)d_ws;

    float* h_all = (float*)(ws + (size_t) 0*MB);   // 8 MB [4096][512]
    float* W_all = (float*)(ws + (size_t) 8*MB);   // 1 MB [512][512]
    float* ssrc  = (float*)(ws + (size_t) 9*MB);   // 128 KB [8][4096]
    float* sdst  = (float*)(ws + (size_t)10*MB);   // 128 KB
    float* hcat  = (float*)(ws + (size_t)11*MB);   // 8 MB [4096][512]
    float* h2    = (float*)(ws + (size_t)19*MB);   // 512 KB [4096][32]
    float* ss2   = (float*)(ws + (size_t)20*MB);   // 16 KB
    float* sd2   = (float*)(ws + (size_t)21*MB);   // 16 KB
    float* pden  = (float*)(ws + (size_t)22*MB);   // 512 KB [4][8][4096]
    float* pnum  = (float*)(ws + (size_t)23*MB);   // 32 MB [4][4096][512]
    float* pnum2 = pnum;                            // reused after reduce1: [8][4096][32] 4MB
    float* pden2 = pden;                            // reused: [8][4096] 128KB
    if (ws_size < (size_t)55*MB) return;            // need 55 MB scratch

    k_repack <<<1024, 256, 0, stream>>>(Watt, W_all);
    k_gemm<64,4><<<dim3(64,8), 256, 0, stream>>>(x, W_all, h_all, NN, 512, 512);
    k_scores1<<<128, 256, 0, stream>>>(h_all, aatt, ssrc, sdst);
    k_attn1 <<<dim3(128,4), 256, 0, stream>>>(h_all, ssrc, sdst, adj, pnum, pden);
    k_reduce1<<<8192, 256, 0, stream>>>(pnum, pden, hcat);
    k_gemm<32,2><<<dim3(64,1), 256, 0, stream>>>(hcat, Wout, h2, NN, 32, 512);
    k_scores2<<<16, 256, 0, stream>>>(h2, aout, ss2, sd2);
    k_attn2 <<<dim3(64,8), 256, 0, stream>>>(h2, ss2, sd2, adj, pnum2, pden2);
    k_reduce2<<<512, 256, 0, stream>>>(pnum2, pden2, out);
}

// Round 2
// 340.502 us; speedup vs baseline: 1.8056x; 1.8056x over previous
//
#include <hip/hip_runtime.h>
#include <math.h>

#define NN 4096      // nodes
#define CC 512       // concat dim = 8 heads * 64
#define MB (1024*1024)

typedef __attribute__((ext_vector_type(8))) __bf16 bf16x8;
typedef __attribute__((ext_vector_type(4))) float f32x4;
typedef unsigned short ushort_t;
typedef unsigned int uint_t;

static __device__ __forceinline__ float lrelu(float x){ return fmaxf(x,0.f) + 0.2f*fminf(x,0.f); }
static __device__ __forceinline__ float elu1(float x){ return x > 0.f ? x : (__expf(x)-1.f); }
static __device__ __forceinline__ ushort_t f2bf(float f){
    union { float f; uint_t u; } v; v.f = f;
    uint_t r = (v.u + 0x7FFFu + ((v.u >> 16) & 1u)) >> 16;
    return (ushort_t)r;
}

// ---- repack W_att [8][512][64] -> W_all [512][512]  (W_all[k][hd*64+f])
__global__ void k_repack(const float* __restrict__ Watt, float* __restrict__ Wall){
    int idx = blockIdx.x*256 + threadIdx.x;            // < 512*512
    int k = idx >> 9, c = idx & 511;
    Wall[idx] = Watt[(c>>6)*(512*64) + k*64 + (c&63)];
}

// ---- generic f32 GEMM: C[M,N]=A[M,K]@B[K,N], row-major. BM=64, BK=16, TM=4.
template<int BN, int TN>
__global__ __launch_bounds__(256) void k_gemm(const float* __restrict__ A,
                                              const float* __restrict__ B,
                                              float* __restrict__ C,
                                              int M, int N, int K){
    constexpr int BM = 64, BK = 16, TM = 4;
    __shared__ float As[BK][BM + 4];
    __shared__ float Bs[BK][BN];
    const int t = threadIdx.x;
    const int i0 = blockIdx.x*BM, j0 = blockIdx.y*BN;
    constexpr int nx = BN / TN;
    const int ty = t / nx, tx = t % nx;
    float acc[TM][TN];
    #pragma unroll
    for(int a=0;a<TM;a++){
        #pragma unroll
        for(int b=0;b<TN;b++) acc[a][b] = 0.f;
    }
    const int ai = t >> 2, ak = (t & 3)*4;
    for(int k0 = 0; k0 < K; k0 += BK){
        __syncthreads();
        float4 av = *(const float4*)&A[(size_t)(i0+ai)*K + k0 + ak];
        As[ak+0][ai]=av.x; As[ak+1][ai]=av.y; As[ak+2][ai]=av.z; As[ak+3][ai]=av.w;
        if constexpr (BN == 64){
            int bk = t >> 4, bj = (t & 15)*4;
            *(float4*)&Bs[bk][bj] = *(const float4*)&B[(size_t)(k0+bk)*N + j0 + bj];
        } else {            // BN == 32
            if (t < 128){
                int bk = t >> 3, bj = (t & 7)*4;
                *(float4*)&Bs[bk][bj] = *(const float4*)&B[(size_t)(k0+bk)*N + j0 + bj];
            }
        }
        __syncthreads();
        #pragma unroll
        for(int k=0;k<BK;k++){
            float4 a4 = *(const float4*)&As[k][ty*TM];
            float ar[4] = {a4.x, a4.y, a4.z, a4.w};
            if constexpr (TN == 4){
                float4 b4 = *(const float4*)&Bs[k][tx*4];
                float br[4] = {b4.x, b4.y, b4.z, b4.w};
                #pragma unroll
                for(int a=0;a<TM;a++){
                    #pragma unroll
                    for(int b=0;b<4;b++) acc[a][b] += ar[a]*br[b];
                }
            } else {
                float2 b2 = *(const float2*)&Bs[k][tx*2];
                #pragma unroll
                for(int a=0;a<TM;a++){ acc[a][0] += ar[a]*b2.x; acc[a][1] += ar[a]*b2.y; }
            }
        }
    }
    #pragma unroll
    for(int a=0;a<TM;a++){
        float* cp = &C[(size_t)(i0 + ty*TM + a)*N + j0 + tx*TN];
        if constexpr (TN == 4){
            float4 v = {acc[a][0], acc[a][1], acc[a][2], acc[a][3]};
            *(float4*)cp = v;
        } else {
            float2 v = {acc[a][0], acc[a][1]};
            *(float2*)cp = v;
        }
    }
}

// ---- transpose h_all [4096][512] f32 -> hT [512][4096] bf16 bits
__global__ __launch_bounds__(256) void k_tr(const float* __restrict__ h, ushort_t* __restrict__ hT){
    __shared__ float tile[32][33];
    const int bj = blockIdx.x*32, bc = blockIdx.y*32;
    const int tx = threadIdx.x & 31, ty = threadIdx.x >> 5;   // 32 x 8
    #pragma unroll
    for(int r=0;r<4;r++)
        tile[ty + r*8][tx] = h[(size_t)(bj + ty + r*8)*512 + bc + tx];
    __syncthreads();
    #pragma unroll
    for(int r=0;r<4;r++)
        hT[(size_t)(bc + ty + r*8)*NN + bj + tx] = f2bf(tile[tx][ty + r*8]);
}

// ---- scores layer1: s_src[hd][i], s_dst[hd][i]
__global__ void k_scores1(const float* __restrict__ hall, const float* __restrict__ aatt,
                          float* __restrict__ ssrc, float* __restrict__ sdst){
    int t = threadIdx.x;
    int hd = t & 7, il = t >> 3;
    int i = blockIdx.x*32 + il;
    const float4* h4 = (const float4*)&hall[(size_t)i*CC + hd*64];
    const float4* a1 = (const float4*)&aatt[hd*128];
    const float4* a2 = (const float4*)&aatt[hd*128 + 64];
    float ss = 0.f, sd = 0.f;
    #pragma unroll
    for(int q=0;q<16;q++){
        float4 h = h4[q], u = a1[q], v = a2[q];
        ss += h.x*u.x + h.y*u.y + h.z*u.z + h.w*u.w;
        sd += h.x*v.x + h.y*v.y + h.z*v.z + h.w*v.w;
    }
    ssrc[hd*NN + i] = ss;
    sdst[hd*NN + i] = sd;
}

// ---- attention layer1 via MFMA.
// grid (128, 4), block 256 = 4 waves; wave handles heads {2w, 2w+1}.
// i-tile = 32 (2 MFMA m-tiles), j-chunk = 1024 (32 K-tiles of 32).
// A-operand w built in-register in fragment layout; B from pre-transposed bf16 hT.
__global__ __launch_bounds__(256) void k_attn1(
        const ushort_t* __restrict__ hT,
        const float* __restrict__ ssrc, const float* __restrict__ sdst,
        const int* __restrict__ adj,
        float* __restrict__ pnum, float* __restrict__ pden){
    const int t = threadIdx.x;
    const int l = t & 63;
    const int hd0 = (t >> 6)*2;
    const int i0 = blockIdx.x*32;
    const int jc = blockIdx.y;
    const int lr = l & 15;     // A row / B col / C col
    const int lg = l >> 4;     // k-group (8 j's each) / C row-group

    f32x4 acc[2][2][4] = {};   // [hd][mh][nt]
    float den[2][2] = {{0.f,0.f},{0.f,0.f}};

    float ssrc_v[2][2];
    #pragma unroll
    for(int hd=0;hd<2;hd++)
        #pragma unroll
        for(int mh=0;mh<2;mh++)
            ssrc_v[hd][mh] = ssrc[(hd0+hd)*NN + i0 + mh*16 + lr];

    for(int jt=0; jt<32; ++jt){
        const int jb = jc*1024 + jt*32 + lg*8;    // this lane's 8-j base
        // B fragments (issue loads early)
        bf16x8 b[2][4];
        #pragma unroll
        for(int hd=0;hd<2;hd++)
            #pragma unroll
            for(int nt=0;nt<4;nt++){
                const int c = (hd0+hd)*64 + nt*16 + lr;
                b[hd][nt] = *(const bf16x8*)&hT[(size_t)c*NN + jb];
            }
        // adjacency for both m-tiles (shared across heads)
        int amv[2][8];
        #pragma unroll
        for(int mh=0;mh<2;mh++){
            const size_t arow = (size_t)(i0 + mh*16 + lr)*NN + jb;
            int4 a0 = *(const int4*)&adj[arow];
            int4 a1 = *(const int4*)&adj[arow + 4];
            amv[mh][0]=a0.x; amv[mh][1]=a0.y; amv[mh][2]=a0.z; amv[mh][3]=a0.w;
            amv[mh][4]=a1.x; amv[mh][5]=a1.y; amv[mh][6]=a1.z; amv[mh][7]=a1.w;
        }
        // A fragments: w in MFMA layout, denominators on the side
        bf16x8 afr[2][2];
        #pragma unroll
        for(int hd=0;hd<2;hd++){
            float4 sd0 = *(const float4*)&sdst[(hd0+hd)*NN + jb];
            float4 sd1 = *(const float4*)&sdst[(hd0+hd)*NN + jb + 4];
            float sdv[8] = {sd0.x,sd0.y,sd0.z,sd0.w, sd1.x,sd1.y,sd1.z,sd1.w};
            #pragma unroll
            for(int mh=0;mh<2;mh++){
                bf16x8 a;
                float d = 0.f;
                #pragma unroll
                for(int e=0;e<8;e++){
                    float s = ssrc_v[hd][mh] + sdv[e];
                    float w = (amv[mh][e] > 0) ? __expf(lrelu(s)) : 0.f;
                    d += w;
                    a[e] = (__bf16)w;
                }
                den[hd][mh] += d;
                afr[hd][mh] = a;
            }
        }
        // MFMA: 16 per j-tile
        #pragma unroll
        for(int hd=0;hd<2;hd++)
            #pragma unroll
            for(int mh=0;mh<2;mh++)
                #pragma unroll
                for(int nt=0;nt<4;nt++)
                    acc[hd][mh][nt] = __builtin_amdgcn_mfma_f32_16x16x32_bf16(
                        afr[hd][mh], b[hd][nt], acc[hd][mh][nt], 0, 0, 0);
    }
    // write pnum partials: C/D layout col=lane&15, row=lg*4+reg
    #pragma unroll
    for(int hd=0;hd<2;hd++)
        #pragma unroll
        for(int mh=0;mh<2;mh++)
            #pragma unroll
            for(int nt=0;nt<4;nt++)
                #pragma unroll
                for(int r=0;r<4;r++){
                    int row = i0 + mh*16 + lg*4 + r;
                    int col = (hd0+hd)*64 + nt*16 + lr;
                    pnum[((size_t)jc*NN + row)*512 + col] = acc[hd][mh][nt][r];
                }
    // denominator: reduce across the 4 k-groups, lanes 0-15 write
    #pragma unroll
    for(int hd=0;hd<2;hd++)
        #pragma unroll
        for(int mh=0;mh<2;mh++){
            float d = den[hd][mh];
            d += __shfl_xor(d, 16);
            d += __shfl_xor(d, 32);
            if (lg == 0)
                pden[((size_t)jc*8 + hd0+hd)*NN + i0 + mh*16 + lr] = d;
        }
}

// ---- reduce layer1: hcat[i][c] = elu( sum(pnum)/sum(pden) )
__global__ void k_reduce1(const float* __restrict__ pnum, const float* __restrict__ pden,
                          float* __restrict__ hcat){
    int idx = blockIdx.x*256 + threadIdx.x;           // < 4096*512
    int i = idx >> 9, c = idx & 511, hd = c >> 6;
    float s = 0.f, d = 0.f;
    #pragma unroll
    for(int jc=0;jc<4;jc++){
        s += pnum[((size_t)jc*NN + i)*512 + c];
        d += pden[((size_t)jc*8 + hd)*NN + i];
    }
    hcat[idx] = elu1(s/d);
}

// ---- scores layer2
__global__ void k_scores2(const float* __restrict__ h2, const float* __restrict__ aout,
                          float* __restrict__ ss2, float* __restrict__ sd2){
    int i = blockIdx.x*256 + threadIdx.x;
    const float4* h4 = (const float4*)&h2[(size_t)i*32];
    const float4* a1 = (const float4*)aout;
    const float4* a2 = (const float4*)&aout[32];
    float ss = 0.f, sd = 0.f;
    #pragma unroll
    for(int q=0;q<8;q++){
        float4 h = h4[q], u = a1[q], v = a2[q];
        ss += h.x*u.x + h.y*u.y + h.z*u.z + h.w*u.w;
        sd += h.x*v.x + h.y*v.y + h.z*v.z + h.w*v.w;
    }
    ss2[i] = ss; sd2[i] = sd;
}

#define FMA4(A, W) { (A).x += (W)*hv.x; (A).y += (W)*hv.y; (A).z += (W)*hv.z; (A).w += (W)*hv.w; }

// ---- attention layer2: i-tile=64, j-tile=16, jchunk=512 (blockIdx.y 0..7)
__global__ __launch_bounds__(256) void k_attn2(const float* __restrict__ h2,
        const float* __restrict__ ss2, const float* __restrict__ sd2,
        const int* __restrict__ adj,
        float* __restrict__ pnum2, float* __restrict__ pden2){
    const int t = threadIdx.x;
    const int i0 = blockIdx.x*64;
    const int jc = blockIdx.y;
    const int fq = t & 7, isub = t >> 3;        // FMA ids: i = i0+isub*2+{0,1}
    const int wii = t & 63, wjq = t >> 6;       // w ids
    __shared__ float h2s[16*32];
    __shared__ float ws2[16*64];                // [jj][ii]
    __shared__ float dpart[4][64];
    float4 acc0 = make_float4(0.f,0.f,0.f,0.f);
    float4 acc1 = make_float4(0.f,0.f,0.f,0.f);
    float den = 0.f;
    const float ssrc_t = ss2[i0 + wii];
    float4* h2s4 = (float4*)h2s;
    const float4* hg4 = (const float4*)h2;

    for(int jt=0; jt<32; ++jt){
        const int j0 = jc*512 + jt*16;
        __syncthreads();
        if (t < 128) h2s4[t] = hg4[(size_t)j0*8 + t];
        {
            const int4 a4 = *(const int4*)&adj[(size_t)(i0+wii)*NN + j0 + wjq*4];
            int am[4] = {a4.x, a4.y, a4.z, a4.w};
            #pragma unroll
            for(int m=0;m<4;m++){
                int jj = wjq*4 + m;
                float e = lrelu(ssrc_t + sd2[j0 + jj]);
                float w = (am[m] > 0) ? __expf(e) : 0.f;
                ws2[jj*64 + wii] = w;
                den += w;
            }
        }
        __syncthreads();
        #pragma unroll
        for(int jj=0;jj<16;jj++){
            float4 hv = h2s4[jj*8 + fq];
            float2 w2 = *(const float2*)&ws2[jj*64 + isub*2];
            FMA4(acc0, w2.x);
            FMA4(acc1, w2.y);
        }
    }
    float4* pn4 = (float4*)pnum2;
    size_t r0 = (size_t)jc*NN + i0 + isub*2;
    pn4[r0*8 + fq] = acc0;
    pn4[(r0+1)*8 + fq] = acc1;
    dpart[wjq][wii] = den;
    __syncthreads();
    if (t < 64)
        pden2[(size_t)jc*NN + i0 + t] = dpart[0][t] + dpart[1][t] + dpart[2][t] + dpart[3][t];
}

// ---- reduce layer2 -> final output
__global__ void k_reduce2(const float* __restrict__ pnum2, const float* __restrict__ pden2,
                          float* __restrict__ out){
    int idx = blockIdx.x*256 + threadIdx.x;       // < 4096*32
    int i = idx >> 5;
    float s = 0.f, d = 0.f;
    #pragma unroll
    for(int jc=0;jc<8;jc++){
        s += pnum2[(size_t)jc*NN*32 + idx];
        d += pden2[(size_t)jc*NN + i];
    }
    out[idx] = elu1(s/d);
}

extern "C" void kernel_launch(void* const* d_in, const int* in_sizes, int n_in,
                              void* d_out, int out_size, void* d_ws, size_t ws_size,
                              hipStream_t stream){
    const float* x    = (const float*)d_in[0];
    const int*   adj  = (const int*)  d_in[1];
    const float* Watt = (const float*)d_in[2];
    const float* aatt = (const float*)d_in[3];
    const float* Wout = (const float*)d_in[4];
    const float* aout = (const float*)d_in[5];
    float* out = (float*)d_out;
    char* ws = (char*)d_ws;

    float*    h_all = (float*)   (ws + (size_t) 0*MB);  // 8 MB [4096][512] (dead after attn1 prep)
    float*    hcat  = (float*)   (ws + (size_t) 0*MB);  // overlays h_all (written in reduce1)
    float*    W_all = (float*)   (ws + (size_t) 8*MB);  // 1 MB
    float*    ssrc  = (float*)   (ws + (size_t) 9*MB);  // 128 KB [8][4096]
    float*    sdst  = (float*)   (ws + (size_t)10*MB);  // 128 KB
    ushort_t* hT    = (ushort_t*)(ws + (size_t)11*MB);  // 4 MB [512][4096] bf16
    float*    h2    = (float*)   (ws + (size_t)19*MB);  // 512 KB [4096][32]
    float*    ss2   = (float*)   (ws + (size_t)20*MB);  // 16 KB
    float*    sd2   = (float*)   (ws + (size_t)21*MB);  // 16 KB
    float*    pden  = (float*)   (ws + (size_t)22*MB);  // 512 KB [4][8][4096]
    float*    pnum  = (float*)   (ws + (size_t)23*MB);  // 32 MB [4][4096][512]
    float*    pnum2 = pnum;                             // reused: [8][4096][32] 4MB
    float*    pden2 = pden;                             // reused: [8][4096] 128KB
    if (ws_size < (size_t)55*MB) return;                // need 55 MB scratch

    k_repack <<<1024, 256, 0, stream>>>(Watt, W_all);
    k_gemm<64,4><<<dim3(64,8), 256, 0, stream>>>(x, W_all, h_all, NN, 512, 512);
    k_tr     <<<dim3(128,16), 256, 0, stream>>>(h_all, hT);
    k_scores1<<<128, 256, 0, stream>>>(h_all, aatt, ssrc, sdst);
    k_attn1  <<<dim3(128,4), 256, 0, stream>>>(hT, ssrc, sdst, adj, pnum, pden);
    k_reduce1<<<8192, 256, 0, stream>>>(pnum, pden, hcat);
    k_gemm<32,2><<<dim3(64,1), 256, 0, stream>>>(hcat, Wout, h2, NN, 32, 512);
    k_scores2<<<16, 256, 0, stream>>>(h2, aout, ss2, sd2);
    k_attn2  <<<dim3(64,8), 256, 0, stream>>>(h2, ss2, sd2, adj, pnum2, pden2);
    k_reduce2<<<512, 256, 0, stream>>>(pnum2, pden2, out);
}